// Round 1
// baseline (1148.961 us; speedup 1.0000x reference)
//
#include <hip/hip_runtime.h>
#include <stdint.h>

#define B_   16
#define C_   192
#define TX_  512
#define TY_  2048
#define K_   384       // 2*C
#define SEG_ 32
#define NEG_INF_ (-1e9f)

// Output layout (floats) in d_out:
//   z_slice : [16,192,32]    @ 0         (98304)
//   ids     : [16] (as f32)  @ 98304     (16)
//   attn    : [16,2048,512]  @ 98320     (16777216)
//   m_p_a   : [16,192,2048]  @ 16875536  (6291456)
//   logs_p_a: [16,192,2048]  @ 23166992  (6291456)

// ---------------------------------------------------------------------------
// K0: build B-matrix [b, k, tx] (k<192: s = exp(-2 logs); k>=192: s*m_p) and
//     c_term[b,tx] = sum_c (-0.5 s m^2 - logs)
// ---------------------------------------------------------------------------
__global__ __launch_bounds__(128) void k_prep(const float* __restrict__ mp,
                                              const float* __restrict__ logsp,
                                              float* __restrict__ Bmat,
                                              float* __restrict__ cterm) {
    int b  = blockIdx.y;
    int tx = blockIdx.x * 128 + threadIdx.x;
    const float* mb = mp    + (size_t)b * C_ * TX_ + tx;
    const float* lb = logsp + (size_t)b * C_ * TX_ + tx;
    float* B0 = Bmat + (size_t)b * K_ * TX_ + tx;
    float acc = 0.f;
    for (int c = 0; c < C_; ++c) {
        float lg = lb[(size_t)c * TX_];
        float m  = mb[(size_t)c * TX_];
        float s  = expf(-2.f * lg);
        B0[(size_t)c * TX_]        = s;
        B0[(size_t)(C_ + c) * TX_] = s * m;
        acc += -0.5f * s * m * m - lg;
    }
    cterm[b * TX_ + tx] = acc;
}

// ---------------------------------------------------------------------------
// K1: neg_cent GEMM.  C[b, ty, tx] = sum_k A[b,k,ty]*B[b,k,tx] + cterm[b,tx]
//     A is derived on the fly from z_p: k<192 -> -0.5*z^2 ; k>=192 -> z.
//     128x128 tile, 256 threads, 8x8 accumulators/thread, K-block 16.
// ---------------------------------------------------------------------------
__global__ __launch_bounds__(256) void k_gemm(const float* __restrict__ zp,
                                              const float* __restrict__ Bmat,
                                              const float* __restrict__ cterm,
                                              float* __restrict__ ncout) {
    __shared__ float As[16][128];
    __shared__ float Bs[16][128];
    int b  = blockIdx.z;
    int m0 = blockIdx.y * 128;   // ty
    int n0 = blockIdx.x * 128;   // tx
    int tid = threadIdx.x;
    int tm = tid >> 4;           // 0..15
    int tn = tid & 15;           // 0..15
    const float* zpb = zp   + (size_t)b * C_ * TY_;
    const float* Bb  = Bmat + (size_t)b * K_ * TX_;

    float acc[8][8];
#pragma unroll
    for (int i = 0; i < 8; ++i)
#pragma unroll
        for (int j = 0; j < 8; ++j) acc[i][j] = 0.f;

    int lrow = tid >> 5;           // 0..7
    int lcol = (tid & 31) << 2;    // 0..124

    for (int k0 = 0; k0 < K_; k0 += 16) {
        // global loads (issued before barrier so they overlap prior compute)
        int ksrc = (k0 < C_) ? k0 : (k0 - C_);
        const float* Ab = zpb + (size_t)(ksrc + lrow) * TY_ + m0 + lcol;
        float4 z0 = *(const float4*)Ab;
        float4 z1 = *(const float4*)(Ab + (size_t)8 * TY_);
        if (k0 < C_) {
            z0.x = -0.5f * z0.x * z0.x; z0.y = -0.5f * z0.y * z0.y;
            z0.z = -0.5f * z0.z * z0.z; z0.w = -0.5f * z0.w * z0.w;
            z1.x = -0.5f * z1.x * z1.x; z1.y = -0.5f * z1.y * z1.y;
            z1.z = -0.5f * z1.z * z1.z; z1.w = -0.5f * z1.w * z1.w;
        }
        const float* Bp = Bb + (size_t)(k0 + lrow) * TX_ + n0 + lcol;
        float4 w0 = *(const float4*)Bp;
        float4 w1 = *(const float4*)(Bp + (size_t)8 * TX_);

        __syncthreads();   // prior iteration's reads done before overwrite
        *(float4*)&As[lrow][lcol]     = z0;
        *(float4*)&As[lrow + 8][lcol] = z1;
        *(float4*)&Bs[lrow][lcol]     = w0;
        *(float4*)&Bs[lrow + 8][lcol] = w1;
        __syncthreads();

#pragma unroll
        for (int kk = 0; kk < 16; ++kk) {
            float4 a0 = *(const float4*)&As[kk][tm * 8];
            float4 a1 = *(const float4*)&As[kk][tm * 8 + 4];
            float4 b0 = *(const float4*)&Bs[kk][tn * 8];
            float4 b1 = *(const float4*)&Bs[kk][tn * 8 + 4];
            float a[8]  = {a0.x, a0.y, a0.z, a0.w, a1.x, a1.y, a1.z, a1.w};
            float bb[8] = {b0.x, b0.y, b0.z, b0.w, b1.x, b1.y, b1.z, b1.w};
#pragma unroll
            for (int i = 0; i < 8; ++i)
#pragma unroll
                for (int j = 0; j < 8; ++j)
                    acc[i][j] = fmaf(a[i], bb[j], acc[i][j]);
        }
    }

    float cadd[8];
#pragma unroll
    for (int j = 0; j < 8; ++j) cadd[j] = cterm[b * TX_ + n0 + tn * 8 + j];

#pragma unroll
    for (int i = 0; i < 8; ++i) {
        int row = m0 + tm * 8 + i;
        float* orow = ncout + ((size_t)b * TY_ + row) * TX_ + n0 + tn * 8;
        float4 o0, o1;
        o0.x = acc[i][0] + cadd[0]; o0.y = acc[i][1] + cadd[1];
        o0.z = acc[i][2] + cadd[2]; o0.w = acc[i][3] + cadd[3];
        o1.x = acc[i][4] + cadd[4]; o1.y = acc[i][5] + cadd[5];
        o1.z = acc[i][6] + cadd[6]; o1.w = acc[i][7] + cadd[7];
        *(float4*)orow       = o0;
        *(float4*)(orow + 4) = o1;
    }
}

// ---------------------------------------------------------------------------
// K2: DP forward. 1 wave per batch, 8 columns per lane (registers),
//     dirn bits (v_shift > v) packed 8 per lane per row -> dirs[b][row][64].
//     neg_cent rows double-buffered in registers, 8-row groups.
// ---------------------------------------------------------------------------
#define LOADG(g, P0, P1)                                                     \
    {                                                                        \
        const float* rp = base + (size_t)(g) * 8 * TX_;                      \
        _Pragma("unroll") for (int r = 0; r < 8; ++r) {                      \
            P0[r] = *(const float4*)(rp + (size_t)r * TX_);                  \
            P1[r] = *(const float4*)(rp + (size_t)r * TX_ + 4);              \
        }                                                                    \
    }

#define PROCG(g, P0, P1)                                                     \
    {                                                                        \
        _Pragma("unroll") for (int r = 0; r < 8; ++r) {                      \
            int row = (g) * 8 + r;                                           \
            if (row < t_y) {                                                 \
                float rc[8] = {P0[r].x, P0[r].y, P0[r].z, P0[r].w,           \
                               P1[r].x, P1[r].y, P1[r].z, P1[r].w};          \
                float left = __shfl_up(v[7], 1);                             \
                if (lane == 0) left = NEG_INF_;                              \
                unsigned by = 0u;                                            \
                _Pragma("unroll") for (int k = 7; k >= 0; --k) {             \
                    float vs = (k == 0) ? left : v[k - 1];                   \
                    if (vs > v[k]) by |= (1u << k);                          \
                    float t = fmaxf(v[k], vs) + rc[k];                       \
                    v[k] = mk[k] ? fmaxf(t, NEG_INF_) : NEG_INF_;            \
                }                                                            \
                db[(size_t)row * 64] = (unsigned char)by;                    \
            }                                                                \
        }                                                                    \
    }

__global__ __launch_bounds__(64) void k_dpfwd(const float* __restrict__ nc,
                                              const int* __restrict__ xl,
                                              const int* __restrict__ yl,
                                              unsigned char* __restrict__ dirs) {
    int b    = blockIdx.x;
    int lane = threadIdx.x;
    int t_x  = xl[b];
    int t_y  = yl[b]; if (t_y > TY_) t_y = TY_;
    const float* base = nc + (size_t)b * TY_ * TX_ + lane * 8;
    unsigned char* db = dirs + (size_t)b * TY_ * 64 + lane;

    int col0 = lane * 8;
    float v[8];
    bool  mk[8];
#pragma unroll
    for (int k = 0; k < 8; ++k) {
        v[k]  = (col0 + k == 0) ? 0.f : NEG_INF_;
        mk[k] = (col0 + k) < t_x;
    }

    float4 c0[8], c1[8], n0[8], n1[8];
    int ng = (t_y + 7) >> 3;

    LOADG(0, c0, c1);
    for (int g = 0; g < ng; g += 2) {
        if (g + 1 < ng) LOADG(g + 1, n0, n1);
        PROCG(g, c0, c1);
        if (g + 1 < ng) {
            if (g + 2 < ng) LOADG(g + 2, c0, c1);
            PROCG(g + 1, n0, n1);
        }
    }
}

// ---------------------------------------------------------------------------
// K3: DP backward. Thread 0 of one wave per batch walks the path using the
//     packed dirn bits; 8 rows per step with a 2-byte speculative window
//     (idx decreases by <=1 per row). Other lanes clear path rows >= t_y.
// ---------------------------------------------------------------------------
__global__ __launch_bounds__(64) void k_dpbwd(const unsigned char* __restrict__ dirs,
                                              const int* __restrict__ xl,
                                              const int* __restrict__ yl,
                                              int* __restrict__ path) {
    int b    = blockIdx.x;
    int lane = threadIdx.x;
    int t_x  = xl[b];
    int t_y  = yl[b]; if (t_y > TY_) t_y = TY_;

    for (int j = t_y + lane; j < TY_; j += 64) path[b * TY_ + j] = -1;
    if (lane != 0) return;

    const unsigned char* db = dirs + (size_t)b * TY_ * 64;
    int* pb = path + b * TY_;
    int idx = t_x - 1;
    int j   = t_y - 1;
    while (j >= 0) {
        int n  = (j + 1 < 8) ? (j + 1) : 8;
        int bs = (idx - 7) >> 3; if (bs < 0) bs = 0;
        int b2 = bs + 1;         if (b2 > 63) b2 = 63;
        unsigned lo[8], hi[8];
#pragma unroll
        for (int r = 0; r < 8; ++r) {
            if (r < n) {
                lo[r] = db[(size_t)(j - r) * 64 + bs];
                hi[r] = db[(size_t)(j - r) * 64 + b2];
            }
        }
#pragma unroll
        for (int r = 0; r < 8; ++r) {
            if (r < n) {
                pb[j - r] = idx;
                int Bi = idx >> 3;
                unsigned byte = (Bi == bs) ? lo[r] : hi[r];
                idx -= (int)((byte >> (idx & 7)) & 1u);
            }
        }
        j -= n;
    }
}

// ---------------------------------------------------------------------------
// K4a: attn one-hot write (overwrites the neg_cent scratch region).
// ---------------------------------------------------------------------------
__global__ __launch_bounds__(256) void k_attn(const int* __restrict__ path,
                                              float* __restrict__ attn) {
    int i   = blockIdx.x * 256 + threadIdx.x;   // over B*TY*TX/4
    int tx0 = (i & 127) << 2;                   // TX/4 = 128
    int bty = i >> 7;                           // b*TY + ty
    int p   = path[bty];
    float4 o;
    o.x = (p == tx0)     ? 1.f : 0.f;
    o.y = (p == tx0 + 1) ? 1.f : 0.f;
    o.z = (p == tx0 + 2) ? 1.f : 0.f;
    o.w = (p == tx0 + 3) ? 1.f : 0.f;
    ((float4*)attn)[i] = o;
}

// ---------------------------------------------------------------------------
// K4b: m_p_a / logs_p_a gather: out[b,c,ty] = (path[ty]>=0) ? in[b,c,path] : 0
// ---------------------------------------------------------------------------
__global__ __launch_bounds__(256) void k_proj(const int* __restrict__ path,
                                              const float* __restrict__ mp,
                                              const float* __restrict__ logsp,
                                              float* __restrict__ mpa,
                                              float* __restrict__ logsa) {
    int i   = blockIdx.x * 256 + threadIdx.x;   // over B*C*TY/4
    int ty0 = (i & 511) << 2;                   // TY/4 = 512
    int bc  = i >> 9;                           // b*C + c
    int b   = bc / C_;
    const int4 p4 = *(const int4*)(path + b * TY_ + ty0);
    const float* mrow = mp    + (size_t)bc * TX_;
    const float* lrow = logsp + (size_t)bc * TX_;
    float4 mo, lo;
    mo.x = (p4.x >= 0) ? mrow[p4.x] : 0.f;  lo.x = (p4.x >= 0) ? lrow[p4.x] : 0.f;
    mo.y = (p4.y >= 0) ? mrow[p4.y] : 0.f;  lo.y = (p4.y >= 0) ? lrow[p4.y] : 0.f;
    mo.z = (p4.z >= 0) ? mrow[p4.z] : 0.f;  lo.z = (p4.z >= 0) ? lrow[p4.z] : 0.f;
    mo.w = (p4.w >= 0) ? mrow[p4.w] : 0.f;  lo.w = (p4.w >= 0) ? lrow[p4.w] : 0.f;
    ((float4*)mpa)[i]   = mo;
    ((float4*)logsa)[i] = lo;
}

// ---------------------------------------------------------------------------
// K4c: random segment slice of z + ids output (replicates ref f32 math).
// ---------------------------------------------------------------------------
__global__ __launch_bounds__(256) void k_slice(const float* __restrict__ z,
                                               const int* __restrict__ yl,
                                               const float* __restrict__ ru,
                                               float* __restrict__ zs,
                                               float* __restrict__ oid) {
    int b = blockIdx.x;
    int safe = yl[b]; if (safe > TY_) safe = TY_;
    int idsmax = safe - SEG_; if (idsmax < 0) idsmax = 0;
    int ids = (int)(ru[b] * ((float)idsmax + 1e-8f));
    int lim = safe - ids;
    for (int t = threadIdx.x; t < C_ * SEG_; t += 256) {
        int c = t >> 5, k = t & 31;
        zs[b * C_ * SEG_ + t] =
            (k < lim) ? z[((size_t)b * C_ + c) * TY_ + ids + k] : 0.f;
    }
    if (threadIdx.x == 0) oid[b] = (float)ids;
}

// ---------------------------------------------------------------------------
extern "C" void kernel_launch(void* const* d_in, const int* in_sizes, int n_in,
                              void* d_out, int out_size, void* d_ws, size_t ws_size,
                              hipStream_t stream) {
    const float* z     = (const float*)d_in[0];
    const float* zp    = (const float*)d_in[1];
    const float* mp    = (const float*)d_in[2];
    const float* logsp = (const float*)d_in[3];
    const int*   xl    = (const int*)d_in[4];
    const int*   yl    = (const int*)d_in[5];
    const float* ru    = (const float*)d_in[6];

    float* out     = (float*)d_out;
    float* o_zs    = out;                  // 98304
    float* o_ids   = out + 98304;          // 16
    float* o_attn  = out + 98320;          // 16777216 (also neg_cent scratch)
    float* o_mpa   = out + 16875536;       // 6291456
    float* o_logsa = out + 23166992;       // 6291456

    float*         Bmat  = (float*)d_ws;                       // 3,145,728 f
    float*         cterm = Bmat + (size_t)B_ * K_ * TX_;       // 8192 f
    unsigned char* dirs  = (unsigned char*)(cterm + B_ * TX_); // 2 MB
    int*           path  = (int*)(dirs + (size_t)B_ * TY_ * 64); // 32768 i32

    hipLaunchKernelGGL(k_prep, dim3(TX_ / 128, B_), dim3(128), 0, stream,
                       mp, logsp, Bmat, cterm);
    hipLaunchKernelGGL(k_gemm, dim3(TX_ / 128, TY_ / 128, B_), dim3(256), 0, stream,
                       zp, Bmat, cterm, o_attn);
    hipLaunchKernelGGL(k_dpfwd, dim3(B_), dim3(64), 0, stream,
                       o_attn, xl, yl, dirs);
    hipLaunchKernelGGL(k_dpbwd, dim3(B_), dim3(64), 0, stream,
                       dirs, xl, yl, path);
    hipLaunchKernelGGL(k_attn, dim3(B_ * TY_ * TX_ / 4 / 256), dim3(256), 0, stream,
                       path, o_attn);
    hipLaunchKernelGGL(k_proj, dim3(B_ * C_ * TY_ / 4 / 256), dim3(256), 0, stream,
                       path, mp, logsp, o_mpa, o_logsa);
    hipLaunchKernelGGL(k_slice, dim3(B_), dim3(256), 0, stream,
                       z, yl, ru, o_zs, o_ids);
}

// Round 2
// 919.785 us; speedup vs baseline: 1.2492x; 1.2492x over previous
//
#include <hip/hip_runtime.h>
#include <stdint.h>

#define B_   16
#define C_   192
#define TX_  512
#define TY_  2048
#define K_   384       // 2*C
#define SEG_ 32
#define NEG_INF_ (-1e9f)

// Output layout (floats) in d_out:
//   z_slice : [16,192,32]    @ 0         (98304)
//   ids     : [16] (as f32)  @ 98304     (16)
//   attn    : [16,2048,512]  @ 98320     (16777216)
//   m_p_a   : [16,192,2048]  @ 16875536  (6291456)
//   logs_p_a: [16,192,2048]  @ 23166992  (6291456)

// ---------------------------------------------------------------------------
// K0: build B-matrix [b, k, tx] (k<192: s = exp(-2 logs); k>=192: s*m_p) and
//     c_term[b,tx] = sum_c (-0.5 s m^2 - logs)
// ---------------------------------------------------------------------------
__global__ __launch_bounds__(128) void k_prep(const float* __restrict__ mp,
                                              const float* __restrict__ logsp,
                                              float* __restrict__ Bmat,
                                              float* __restrict__ cterm) {
    int b  = blockIdx.y;
    int tx = blockIdx.x * 128 + threadIdx.x;
    const float* mb = mp    + (size_t)b * C_ * TX_ + tx;
    const float* lb = logsp + (size_t)b * C_ * TX_ + tx;
    float* B0 = Bmat + (size_t)b * K_ * TX_ + tx;
    float acc = 0.f;
    for (int c = 0; c < C_; ++c) {
        float lg = lb[(size_t)c * TX_];
        float m  = mb[(size_t)c * TX_];
        float s  = expf(-2.f * lg);
        B0[(size_t)c * TX_]        = s;
        B0[(size_t)(C_ + c) * TX_] = s * m;
        acc += -0.5f * s * m * m - lg;
    }
    cterm[b * TX_ + tx] = acc;
}

// ---------------------------------------------------------------------------
// K1: neg_cent GEMM.  C[b, ty, tx] = sum_k A[b,k,ty]*B[b,k,tx] + cterm[b,tx]
//     A is derived on the fly from z_p: k<192 -> -0.5*z^2 ; k>=192 -> z.
//     128x128 tile, 256 threads, 8x8 accumulators/thread, K-block 16.
// ---------------------------------------------------------------------------
__global__ __launch_bounds__(256) void k_gemm(const float* __restrict__ zp,
                                              const float* __restrict__ Bmat,
                                              const float* __restrict__ cterm,
                                              float* __restrict__ ncout) {
    __shared__ float As[16][128];
    __shared__ float Bs[16][128];
    int b  = blockIdx.z;
    int m0 = blockIdx.y * 128;   // ty
    int n0 = blockIdx.x * 128;   // tx
    int tid = threadIdx.x;
    int tm = tid >> 4;           // 0..15
    int tn = tid & 15;           // 0..15
    const float* zpb = zp   + (size_t)b * C_ * TY_;
    const float* Bb  = Bmat + (size_t)b * K_ * TX_;

    float acc[8][8];
#pragma unroll
    for (int i = 0; i < 8; ++i)
#pragma unroll
        for (int j = 0; j < 8; ++j) acc[i][j] = 0.f;

    int lrow = tid >> 5;           // 0..7
    int lcol = (tid & 31) << 2;    // 0..124

    for (int k0 = 0; k0 < K_; k0 += 16) {
        int ksrc = (k0 < C_) ? k0 : (k0 - C_);
        const float* Ab = zpb + (size_t)(ksrc + lrow) * TY_ + m0 + lcol;
        float4 z0 = *(const float4*)Ab;
        float4 z1 = *(const float4*)(Ab + (size_t)8 * TY_);
        if (k0 < C_) {
            z0.x = -0.5f * z0.x * z0.x; z0.y = -0.5f * z0.y * z0.y;
            z0.z = -0.5f * z0.z * z0.z; z0.w = -0.5f * z0.w * z0.w;
            z1.x = -0.5f * z1.x * z1.x; z1.y = -0.5f * z1.y * z1.y;
            z1.z = -0.5f * z1.z * z1.z; z1.w = -0.5f * z1.w * z1.w;
        }
        const float* Bp = Bb + (size_t)(k0 + lrow) * TX_ + n0 + lcol;
        float4 w0 = *(const float4*)Bp;
        float4 w1 = *(const float4*)(Bp + (size_t)8 * TX_);

        __syncthreads();   // prior iteration's reads done before overwrite
        *(float4*)&As[lrow][lcol]     = z0;
        *(float4*)&As[lrow + 8][lcol] = z1;
        *(float4*)&Bs[lrow][lcol]     = w0;
        *(float4*)&Bs[lrow + 8][lcol] = w1;
        __syncthreads();

#pragma unroll
        for (int kk = 0; kk < 16; ++kk) {
            float4 a0 = *(const float4*)&As[kk][tm * 8];
            float4 a1 = *(const float4*)&As[kk][tm * 8 + 4];
            float4 b0 = *(const float4*)&Bs[kk][tn * 8];
            float4 b1 = *(const float4*)&Bs[kk][tn * 8 + 4];
            float a[8]  = {a0.x, a0.y, a0.z, a0.w, a1.x, a1.y, a1.z, a1.w};
            float bb[8] = {b0.x, b0.y, b0.z, b0.w, b1.x, b1.y, b1.z, b1.w};
#pragma unroll
            for (int i = 0; i < 8; ++i)
#pragma unroll
                for (int j = 0; j < 8; ++j)
                    acc[i][j] = fmaf(a[i], bb[j], acc[i][j]);
        }
    }

    float cadd[8];
#pragma unroll
    for (int j = 0; j < 8; ++j) cadd[j] = cterm[b * TX_ + n0 + tn * 8 + j];

#pragma unroll
    for (int i = 0; i < 8; ++i) {
        int row = m0 + tm * 8 + i;
        float* orow = ncout + ((size_t)b * TY_ + row) * TX_ + n0 + tn * 8;
        float4 o0, o1;
        o0.x = acc[i][0] + cadd[0]; o0.y = acc[i][1] + cadd[1];
        o0.z = acc[i][2] + cadd[2]; o0.w = acc[i][3] + cadd[3];
        o1.x = acc[i][4] + cadd[4]; o1.y = acc[i][5] + cadd[5];
        o1.z = acc[i][6] + cadd[6]; o1.w = acc[i][7] + cadd[7];
        *(float4*)orow       = o0;
        *(float4*)(orow + 4) = o1;
    }
}

// ---------------------------------------------------------------------------
// K2: fused DP forward + backward. One block (1 wave) per batch.
//     Forward: 8 columns/lane in registers, dirn bits packed 8/lane/row into
//     LDS (2048 rows x 64 B = 128 KiB, dynamic LDS).
//     Backward: lane 0 walks the path reading LDS (8-row groups, 2-byte
//     speculative window since idx decreases <=1 per row).
// ---------------------------------------------------------------------------
#define LOADG(g, P0, P1)                                                     \
    {                                                                        \
        const float* rp = base + (size_t)(g) * 8 * TX_;                      \
        _Pragma("unroll") for (int r = 0; r < 8; ++r) {                      \
            P0[r] = *(const float4*)(rp + (size_t)r * TX_);                  \
            P1[r] = *(const float4*)(rp + (size_t)r * TX_ + 4);              \
        }                                                                    \
    }

#define PROCG(g, P0, P1)                                                     \
    {                                                                        \
        _Pragma("unroll") for (int r = 0; r < 8; ++r) {                      \
            int row = (g) * 8 + r;                                           \
            if (row < t_y) {                                                 \
                float rc[8] = {P0[r].x, P0[r].y, P0[r].z, P0[r].w,           \
                               P1[r].x, P1[r].y, P1[r].z, P1[r].w};          \
                float left = __shfl_up(v[7], 1);                             \
                if (lane == 0) left = NEG_INF_;                              \
                unsigned by = 0u;                                            \
                _Pragma("unroll") for (int k = 7; k >= 0; --k) {             \
                    float vs = (k == 0) ? left : v[k - 1];                   \
                    if (vs > v[k]) by |= (1u << k);                          \
                    float t = fmaxf(v[k], vs) + rc[k];                       \
                    v[k] = mk[k] ? fmaxf(t, NEG_INF_) : NEG_INF_;            \
                }                                                            \
                sdirs[row * 64 + lane] = (unsigned char)by;                  \
            }                                                                \
        }                                                                    \
    }

__global__ __launch_bounds__(64) void k_dp(const float* __restrict__ nc,
                                           const int* __restrict__ xl,
                                           const int* __restrict__ yl,
                                           int* __restrict__ path) {
    extern __shared__ unsigned char sdirs[];   // TY_*64 = 131072 bytes
    int b    = blockIdx.x;
    int lane = threadIdx.x;
    int t_x  = xl[b];
    int t_y  = yl[b]; if (t_y > TY_) t_y = TY_;
    const float* base = nc + (size_t)b * TY_ * TX_ + lane * 8;

    int col0 = lane * 8;
    float v[8];
    bool  mk[8];
#pragma unroll
    for (int k = 0; k < 8; ++k) {
        v[k]  = (col0 + k == 0) ? 0.f : NEG_INF_;
        mk[k] = (col0 + k) < t_x;
    }

    float4 c0[8], c1[8], n0[8], n1[8];
    int ng = (t_y + 7) >> 3;

    LOADG(0, c0, c1);
    for (int g = 0; g < ng; g += 2) {
        if (g + 1 < ng) LOADG(g + 1, n0, n1);
        PROCG(g, c0, c1);
        if (g + 1 < ng) {
            if (g + 2 < ng) LOADG(g + 2, c0, c1);
            PROCG(g + 1, n0, n1);
        }
    }

    __syncthreads();   // LDS dirn bytes visible

    int* pb = path + b * TY_;
    for (int j = t_y + lane; j < TY_; j += 64) pb[j] = -1;

    if (lane == 0) {
        int idx = t_x - 1;
        int j   = t_y - 1;
        while (j >= 0) {
            int n  = (j + 1 < 8) ? (j + 1) : 8;
            int bs = (idx - 7) >> 3; if (bs < 0) bs = 0;
            int b2 = bs + 1;         if (b2 > 63) b2 = 63;
            unsigned lo[8], hi[8];
#pragma unroll
            for (int r = 0; r < 8; ++r) {
                if (r < n) {
                    lo[r] = sdirs[(j - r) * 64 + bs];
                    hi[r] = sdirs[(j - r) * 64 + b2];
                }
            }
#pragma unroll
            for (int r = 0; r < 8; ++r) {
                if (r < n) {
                    pb[j - r] = idx;
                    int Bi = idx >> 3;
                    unsigned byte = (Bi == bs) ? lo[r] : hi[r];
                    idx -= (int)((byte >> (idx & 7)) & 1u);
                }
            }
            j -= n;
        }
    }
}

// ---------------------------------------------------------------------------
// K4a: attn one-hot write (overwrites the neg_cent scratch region).
// ---------------------------------------------------------------------------
__global__ __launch_bounds__(256) void k_attn(const int* __restrict__ path,
                                              float* __restrict__ attn) {
    int i   = blockIdx.x * 256 + threadIdx.x;   // over B*TY*TX/4
    int tx0 = (i & 127) << 2;                   // TX/4 = 128
    int bty = i >> 7;                           // b*TY + ty
    int p   = path[bty];
    float4 o;
    o.x = (p == tx0)     ? 1.f : 0.f;
    o.y = (p == tx0 + 1) ? 1.f : 0.f;
    o.z = (p == tx0 + 2) ? 1.f : 0.f;
    o.w = (p == tx0 + 3) ? 1.f : 0.f;
    ((float4*)attn)[i] = o;
}

// ---------------------------------------------------------------------------
// K4b: m_p_a / logs_p_a gather: out[b,c,ty] = (path[ty]>=0) ? in[b,c,path] : 0
// ---------------------------------------------------------------------------
__global__ __launch_bounds__(256) void k_proj(const int* __restrict__ path,
                                              const float* __restrict__ mp,
                                              const float* __restrict__ logsp,
                                              float* __restrict__ mpa,
                                              float* __restrict__ logsa) {
    int i   = blockIdx.x * 256 + threadIdx.x;   // over B*C*TY/4
    int ty0 = (i & 511) << 2;                   // TY/4 = 512
    int bc  = i >> 9;                           // b*C + c
    int b   = bc / C_;
    const int4 p4 = *(const int4*)(path + b * TY_ + ty0);
    const float* mrow = mp    + (size_t)bc * TX_;
    const float* lrow = logsp + (size_t)bc * TX_;
    float4 mo, lo;
    mo.x = (p4.x >= 0) ? mrow[p4.x] : 0.f;  lo.x = (p4.x >= 0) ? lrow[p4.x] : 0.f;
    mo.y = (p4.y >= 0) ? mrow[p4.y] : 0.f;  lo.y = (p4.y >= 0) ? lrow[p4.y] : 0.f;
    mo.z = (p4.z >= 0) ? mrow[p4.z] : 0.f;  lo.z = (p4.z >= 0) ? lrow[p4.z] : 0.f;
    mo.w = (p4.w >= 0) ? mrow[p4.w] : 0.f;  lo.w = (p4.w >= 0) ? lrow[p4.w] : 0.f;
    ((float4*)mpa)[i]   = mo;
    ((float4*)logsa)[i] = lo;
}

// ---------------------------------------------------------------------------
// K4c: random segment slice of z + ids output (replicates ref f32 math).
// ---------------------------------------------------------------------------
__global__ __launch_bounds__(256) void k_slice(const float* __restrict__ z,
                                               const int* __restrict__ yl,
                                               const float* __restrict__ ru,
                                               float* __restrict__ zs,
                                               float* __restrict__ oid) {
    int b = blockIdx.x;
    int safe = yl[b]; if (safe > TY_) safe = TY_;
    int idsmax = safe - SEG_; if (idsmax < 0) idsmax = 0;
    int ids = (int)(ru[b] * ((float)idsmax + 1e-8f));
    int lim = safe - ids;
    for (int t = threadIdx.x; t < C_ * SEG_; t += 256) {
        int c = t >> 5, k = t & 31;
        zs[b * C_ * SEG_ + t] =
            (k < lim) ? z[((size_t)b * C_ + c) * TY_ + ids + k] : 0.f;
    }
    if (threadIdx.x == 0) oid[b] = (float)ids;
}

// ---------------------------------------------------------------------------
extern "C" void kernel_launch(void* const* d_in, const int* in_sizes, int n_in,
                              void* d_out, int out_size, void* d_ws, size_t ws_size,
                              hipStream_t stream) {
    const float* z     = (const float*)d_in[0];
    const float* zp    = (const float*)d_in[1];
    const float* mp    = (const float*)d_in[2];
    const float* logsp = (const float*)d_in[3];
    const int*   xl    = (const int*)d_in[4];
    const int*   yl    = (const int*)d_in[5];
    const float* ru    = (const float*)d_in[6];

    float* out     = (float*)d_out;
    float* o_zs    = out;                  // 98304
    float* o_ids   = out + 98304;          // 16
    float* o_attn  = out + 98320;          // 16777216 (also neg_cent scratch)
    float* o_mpa   = out + 16875536;       // 6291456
    float* o_logsa = out + 23166992;       // 6291456

    float* Bmat  = (float*)d_ws;                        // 3,145,728 f
    float* cterm = Bmat + (size_t)B_ * K_ * TX_;        // 8192 f
    int*   path  = (int*)(cterm + B_ * TX_);            // 32768 i32

    // allow 128 KiB dynamic LDS for the fused DP kernel (host-side, not a
    // stream op — safe under graph capture; idempotent, called every launch)
    hipFuncSetAttribute((const void*)k_dp,
                        hipFuncAttributeMaxDynamicSharedMemorySize,
                        TY_ * 64);

    hipLaunchKernelGGL(k_prep, dim3(TX_ / 128, B_), dim3(128), 0, stream,
                       mp, logsp, Bmat, cterm);
    hipLaunchKernelGGL(k_gemm, dim3(TX_ / 128, TY_ / 128, B_), dim3(256), 0, stream,
                       zp, Bmat, cterm, o_attn);
    hipLaunchKernelGGL(k_dp, dim3(B_), dim3(64), TY_ * 64, stream,
                       o_attn, xl, yl, path);
    hipLaunchKernelGGL(k_attn, dim3(B_ * TY_ * TX_ / 4 / 256), dim3(256), 0, stream,
                       path, o_attn);
    hipLaunchKernelGGL(k_proj, dim3(B_ * C_ * TY_ / 4 / 256), dim3(256), 0, stream,
                       path, mp, logsp, o_mpa, o_logsa);
    hipLaunchKernelGGL(k_slice, dim3(B_), dim3(256), 0, stream,
                       z, yl, ru, o_zs, o_ids);
}

// Round 3
// 778.604 us; speedup vs baseline: 1.4757x; 1.1813x over previous
//
#include <hip/hip_runtime.h>
#include <stdint.h>

#define B_   16
#define C_   192
#define TX_  512
#define TY_  2048
#define K_   384       // 2*C
#define SEG_ 32
#define NEG_INF_ (-1e9f)

// Output layout (floats) in d_out:
//   z_slice : [16,192,32]    @ 0         (98304)
//   ids     : [16] (as f32)  @ 98304     (16)
//   attn    : [16,2048,512]  @ 98320     (16777216)
//   m_p_a   : [16,192,2048]  @ 16875536  (6291456)
//   logs_p_a: [16,192,2048]  @ 23166992  (6291456)

// ---------------------------------------------------------------------------
// K0: build B-matrix [b, k, tx] (k<192: s = exp(-2 logs); k>=192: s*m_p) and
//     c_term[b,tx] = sum_c (-0.5 s m^2 - logs)
// ---------------------------------------------------------------------------
__global__ __launch_bounds__(128) void k_prep(const float* __restrict__ mp,
                                              const float* __restrict__ logsp,
                                              float* __restrict__ Bmat,
                                              float* __restrict__ cterm) {
    int b  = blockIdx.y;
    int tx = blockIdx.x * 128 + threadIdx.x;
    const float* mb = mp    + (size_t)b * C_ * TX_ + tx;
    const float* lb = logsp + (size_t)b * C_ * TX_ + tx;
    float* B0 = Bmat + (size_t)b * K_ * TX_ + tx;
    float acc = 0.f;
    for (int c = 0; c < C_; ++c) {
        float lg = lb[(size_t)c * TX_];
        float m  = mb[(size_t)c * TX_];
        float s  = expf(-2.f * lg);
        B0[(size_t)c * TX_]        = s;
        B0[(size_t)(C_ + c) * TX_] = s * m;
        acc += -0.5f * s * m * m - lg;
    }
    cterm[b * TX_ + tx] = acc;
}

// ---------------------------------------------------------------------------
// K1: neg_cent GEMM.  C[b, ty, tx] = sum_k A[b,k,ty]*B[b,k,tx] + cterm[b,tx]
//     A is derived on the fly from z_p: k<192 -> -0.5*z^2 ; k>=192 -> z.
//     128x128 tile, 256 threads, 8x8 accumulators/thread, K-block 16.
// ---------------------------------------------------------------------------
__global__ __launch_bounds__(256) void k_gemm(const float* __restrict__ zp,
                                              const float* __restrict__ Bmat,
                                              const float* __restrict__ cterm,
                                              float* __restrict__ ncout) {
    __shared__ float As[16][128];
    __shared__ float Bs[16][128];
    int b  = blockIdx.z;
    int m0 = blockIdx.y * 128;   // ty
    int n0 = blockIdx.x * 128;   // tx
    int tid = threadIdx.x;
    int tm = tid >> 4;           // 0..15
    int tn = tid & 15;           // 0..15
    const float* zpb = zp   + (size_t)b * C_ * TY_;
    const float* Bb  = Bmat + (size_t)b * K_ * TX_;

    float acc[8][8];
#pragma unroll
    for (int i = 0; i < 8; ++i)
#pragma unroll
        for (int j = 0; j < 8; ++j) acc[i][j] = 0.f;

    int lrow = tid >> 5;           // 0..7
    int lcol = (tid & 31) << 2;    // 0..124

    for (int k0 = 0; k0 < K_; k0 += 16) {
        int ksrc = (k0 < C_) ? k0 : (k0 - C_);
        const float* Ab = zpb + (size_t)(ksrc + lrow) * TY_ + m0 + lcol;
        float4 z0 = *(const float4*)Ab;
        float4 z1 = *(const float4*)(Ab + (size_t)8 * TY_);
        if (k0 < C_) {
            z0.x = -0.5f * z0.x * z0.x; z0.y = -0.5f * z0.y * z0.y;
            z0.z = -0.5f * z0.z * z0.z; z0.w = -0.5f * z0.w * z0.w;
            z1.x = -0.5f * z1.x * z1.x; z1.y = -0.5f * z1.y * z1.y;
            z1.z = -0.5f * z1.z * z1.z; z1.w = -0.5f * z1.w * z1.w;
        }
        const float* Bp = Bb + (size_t)(k0 + lrow) * TX_ + n0 + lcol;
        float4 w0 = *(const float4*)Bp;
        float4 w1 = *(const float4*)(Bp + (size_t)8 * TX_);

        __syncthreads();   // prior iteration's reads done before overwrite
        *(float4*)&As[lrow][lcol]     = z0;
        *(float4*)&As[lrow + 8][lcol] = z1;
        *(float4*)&Bs[lrow][lcol]     = w0;
        *(float4*)&Bs[lrow + 8][lcol] = w1;
        __syncthreads();

#pragma unroll
        for (int kk = 0; kk < 16; ++kk) {
            float4 a0 = *(const float4*)&As[kk][tm * 8];
            float4 a1 = *(const float4*)&As[kk][tm * 8 + 4];
            float4 b0 = *(const float4*)&Bs[kk][tn * 8];
            float4 b1 = *(const float4*)&Bs[kk][tn * 8 + 4];
            float a[8]  = {a0.x, a0.y, a0.z, a0.w, a1.x, a1.y, a1.z, a1.w};
            float bb[8] = {b0.x, b0.y, b0.z, b0.w, b1.x, b1.y, b1.z, b1.w};
#pragma unroll
            for (int i = 0; i < 8; ++i)
#pragma unroll
                for (int j = 0; j < 8; ++j)
                    acc[i][j] = fmaf(a[i], bb[j], acc[i][j]);
        }
    }

    float cadd[8];
#pragma unroll
    for (int j = 0; j < 8; ++j) cadd[j] = cterm[b * TX_ + n0 + tn * 8 + j];

#pragma unroll
    for (int i = 0; i < 8; ++i) {
        int row = m0 + tm * 8 + i;
        float* orow = ncout + ((size_t)b * TY_ + row) * TX_ + n0 + tn * 8;
        float4 o0, o1;
        o0.x = acc[i][0] + cadd[0]; o0.y = acc[i][1] + cadd[1];
        o0.z = acc[i][2] + cadd[2]; o0.w = acc[i][3] + cadd[3];
        o1.x = acc[i][4] + cadd[4]; o1.y = acc[i][5] + cadd[5];
        o1.z = acc[i][6] + cadd[6]; o1.w = acc[i][7] + cadd[7];
        *(float4*)orow       = o0;
        *(float4*)(orow + 4) = o1;
    }
}

// ---------------------------------------------------------------------------
// K2: fused DP forward + backward. One block (1 wave) per batch.
//
// Forward: 8 columns/lane in registers. NO masking/clamping: masked columns
// (>= t_x) only propagate rightward (v_new[k] reads v[k-1]) so they never
// feed valid columns; unclamped unreachable values drift < ~2e6 below -1e9,
// still far below any real path value, so all dirn bits the backward walk
// can consult are identical to the reference's.
// dirn bits packed 8/lane/row, 4 rows per dword -> one ds_write_b32 per
// 4 rows. LDS layout: dword[(row>>2)*64 + lane] holds rows 4q..4q+3.
// Double-buffered 8-row groups with sched_barrier(0) pinning the prefetch
// (without it the compiler sinks loads to first use and the pipeline dies —
// round-2 profile: 660 cyc/row, VGPR_Count 76 vs 128 declared buffers).
//
// Backward: lane 0 walks the path reading LDS bytes (8-row groups, 2-byte
// speculative window since idx decreases <=1 per row).
// ---------------------------------------------------------------------------
#define LOADG(g, P0, P1)                                                     \
    {                                                                        \
        const float* rp = base + (size_t)(g) * 8 * TX_;                      \
        _Pragma("unroll") for (int r = 0; r < 8; ++r) {                      \
            P0[r] = *(const float4*)(rp + (size_t)r * TX_);                  \
            P1[r] = *(const float4*)(rp + (size_t)r * TX_ + 4);              \
        }                                                                    \
    }

#define PROCG(g, P0, P1)                                                     \
    {                                                                        \
        unsigned dw0 = 0u, dw1 = 0u;                                         \
        _Pragma("unroll") for (int r = 0; r < 8; ++r) {                      \
            float rc[8] = {P0[r].x, P0[r].y, P0[r].z, P0[r].w,               \
                           P1[r].x, P1[r].y, P1[r].z, P1[r].w};              \
            float left = __shfl_up(v[7], 1);                                 \
            if (lane == 0) left = NEG_INF_;                                  \
            unsigned by = 0u;                                                \
            _Pragma("unroll") for (int k = 7; k >= 0; --k) {                 \
                float vs = (k == 0) ? left : v[k - 1];                       \
                if (vs > v[k]) by |= (1u << k);                              \
                v[k] = fmaxf(v[k], vs) + rc[k];                              \
            }                                                                \
            if (r < 4) dw0 |= by << (8 * r);                                 \
            else       dw1 |= by << (8 * (r - 4));                           \
        }                                                                    \
        sdirs32[((g) * 2) * 64 + lane]     = dw0;                            \
        sdirs32[((g) * 2 + 1) * 64 + lane] = dw1;                            \
    }

__global__ __launch_bounds__(64, 1) void k_dp(const float* __restrict__ nc,
                                              const int* __restrict__ xl,
                                              const int* __restrict__ yl,
                                              int* __restrict__ path) {
    extern __shared__ unsigned char sdirs[];   // TY_*64 = 131072 bytes
    unsigned* sdirs32 = (unsigned*)sdirs;
    int b    = blockIdx.x;
    int lane = threadIdx.x;
    int t_x  = xl[b];
    int t_y  = yl[b]; if (t_y > TY_) t_y = TY_;
    const float* base = nc + (size_t)b * TY_ * TX_ + lane * 8;

    int col0 = lane * 8;
    float v[8];
#pragma unroll
    for (int k = 0; k < 8; ++k) v[k] = (col0 + k == 0) ? 0.f : NEG_INF_;

    float4 c0[8], c1[8], n0[8], n1[8];
    int ng = (t_y + 7) >> 3;

    LOADG(0, c0, c1);
    for (int g = 0; g < ng; g += 2) {
        if (g + 1 < ng) LOADG(g + 1, n0, n1);
        __builtin_amdgcn_sched_barrier(0);     // keep prefetch ahead of compute
        PROCG(g, c0, c1);
        if (g + 1 < ng) {
            if (g + 2 < ng) LOADG(g + 2, c0, c1);
            __builtin_amdgcn_sched_barrier(0);
            PROCG(g + 1, n0, n1);
        }
    }

    __syncthreads();   // LDS dirn bits visible

    int* pb = path + b * TY_;
    for (int j = t_y + lane; j < TY_; j += 64) pb[j] = -1;

    if (lane == 0) {
        int idx = t_x - 1;
        int j   = t_y - 1;
        while (j >= 0) {
            int n  = (j + 1 < 8) ? (j + 1) : 8;
            int bs = (idx - 7) >> 3; if (bs < 0) bs = 0;
            int b2 = bs + 1;         if (b2 > 63) b2 = 63;
            unsigned lo[8], hi[8];
#pragma unroll
            for (int r = 0; r < 8; ++r) {
                if (r < n) {
                    int jr = j - r;
                    int rb = (jr >> 2) * 256 + (jr & 3);
                    lo[r] = sdirs[rb + bs * 4];
                    hi[r] = sdirs[rb + b2 * 4];
                }
            }
#pragma unroll
            for (int r = 0; r < 8; ++r) {
                if (r < n) {
                    pb[j - r] = idx;
                    int Bi = idx >> 3;
                    unsigned byte = (Bi == bs) ? lo[r] : hi[r];
                    idx -= (int)((byte >> (idx & 7)) & 1u);
                }
            }
            j -= n;
        }
    }
}

// ---------------------------------------------------------------------------
// K4a: attn one-hot write (overwrites the neg_cent scratch region).
// ---------------------------------------------------------------------------
__global__ __launch_bounds__(256) void k_attn(const int* __restrict__ path,
                                              float* __restrict__ attn) {
    int i   = blockIdx.x * 256 + threadIdx.x;   // over B*TY*TX/4
    int tx0 = (i & 127) << 2;                   // TX/4 = 128
    int bty = i >> 7;                           // b*TY + ty
    int p   = path[bty];
    float4 o;
    o.x = (p == tx0)     ? 1.f : 0.f;
    o.y = (p == tx0 + 1) ? 1.f : 0.f;
    o.z = (p == tx0 + 2) ? 1.f : 0.f;
    o.w = (p == tx0 + 3) ? 1.f : 0.f;
    ((float4*)attn)[i] = o;
}

// ---------------------------------------------------------------------------
// K4b: m_p_a / logs_p_a gather: out[b,c,ty] = (path[ty]>=0) ? in[b,c,path] : 0
// ---------------------------------------------------------------------------
__global__ __launch_bounds__(256) void k_proj(const int* __restrict__ path,
                                              const float* __restrict__ mp,
                                              const float* __restrict__ logsp,
                                              float* __restrict__ mpa,
                                              float* __restrict__ logsa) {
    int i   = blockIdx.x * 256 + threadIdx.x;   // over B*C*TY/4
    int ty0 = (i & 511) << 2;                   // TY/4 = 512
    int bc  = i >> 9;                           // b*C + c
    int b   = bc / C_;
    const int4 p4 = *(const int4*)(path + b * TY_ + ty0);
    const float* mrow = mp    + (size_t)bc * TX_;
    const float* lrow = logsp + (size_t)bc * TX_;
    float4 mo, lo;
    mo.x = (p4.x >= 0) ? mrow[p4.x] : 0.f;  lo.x = (p4.x >= 0) ? lrow[p4.x] : 0.f;
    mo.y = (p4.y >= 0) ? mrow[p4.y] : 0.f;  lo.y = (p4.y >= 0) ? lrow[p4.y] : 0.f;
    mo.z = (p4.z >= 0) ? mrow[p4.z] : 0.f;  lo.z = (p4.z >= 0) ? lrow[p4.z] : 0.f;
    mo.w = (p4.w >= 0) ? mrow[p4.w] : 0.f;  lo.w = (p4.w >= 0) ? lrow[p4.w] : 0.f;
    ((float4*)mpa)[i]   = mo;
    ((float4*)logsa)[i] = lo;
}

// ---------------------------------------------------------------------------
// K4c: random segment slice of z + ids output (replicates ref f32 math).
// ---------------------------------------------------------------------------
__global__ __launch_bounds__(256) void k_slice(const float* __restrict__ z,
                                               const int* __restrict__ yl,
                                               const float* __restrict__ ru,
                                               float* __restrict__ zs,
                                               float* __restrict__ oid) {
    int b = blockIdx.x;
    int safe = yl[b]; if (safe > TY_) safe = TY_;
    int idsmax = safe - SEG_; if (idsmax < 0) idsmax = 0;
    int ids = (int)(ru[b] * ((float)idsmax + 1e-8f));
    int lim = safe - ids;
    for (int t = threadIdx.x; t < C_ * SEG_; t += 256) {
        int c = t >> 5, k = t & 31;
        zs[b * C_ * SEG_ + t] =
            (k < lim) ? z[((size_t)b * C_ + c) * TY_ + ids + k] : 0.f;
    }
    if (threadIdx.x == 0) oid[b] = (float)ids;
}

// ---------------------------------------------------------------------------
extern "C" void kernel_launch(void* const* d_in, const int* in_sizes, int n_in,
                              void* d_out, int out_size, void* d_ws, size_t ws_size,
                              hipStream_t stream) {
    const float* z     = (const float*)d_in[0];
    const float* zp    = (const float*)d_in[1];
    const float* mp    = (const float*)d_in[2];
    const float* logsp = (const float*)d_in[3];
    const int*   xl    = (const int*)d_in[4];
    const int*   yl    = (const int*)d_in[5];
    const float* ru    = (const float*)d_in[6];

    float* out     = (float*)d_out;
    float* o_zs    = out;                  // 98304
    float* o_ids   = out + 98304;          // 16
    float* o_attn  = out + 98320;          // 16777216 (also neg_cent scratch)
    float* o_mpa   = out + 16875536;       // 6291456
    float* o_logsa = out + 23166992;       // 6291456

    float* Bmat  = (float*)d_ws;                        // 3,145,728 f
    float* cterm = Bmat + (size_t)B_ * K_ * TX_;        // 8192 f
    int*   path  = (int*)(cterm + B_ * TX_);            // 32768 i32

    // allow 128 KiB dynamic LDS for the fused DP kernel (host-side, not a
    // stream op — safe under graph capture; idempotent, called every launch)
    hipFuncSetAttribute((const void*)k_dp,
                        hipFuncAttributeMaxDynamicSharedMemorySize,
                        TY_ * 64);

    hipLaunchKernelGGL(k_prep, dim3(TX_ / 128, B_), dim3(128), 0, stream,
                       mp, logsp, Bmat, cterm);
    hipLaunchKernelGGL(k_gemm, dim3(TX_ / 128, TY_ / 128, B_), dim3(256), 0, stream,
                       zp, Bmat, cterm, o_attn);
    hipLaunchKernelGGL(k_dp, dim3(B_), dim3(64), TY_ * 64, stream,
                       o_attn, xl, yl, path);
    hipLaunchKernelGGL(k_attn, dim3(B_ * TY_ * TX_ / 4 / 256), dim3(256), 0, stream,
                       path, o_attn);
    hipLaunchKernelGGL(k_proj, dim3(B_ * C_ * TY_ / 4 / 256), dim3(256), 0, stream,
                       path, mp, logsp, o_mpa, o_logsa);
    hipLaunchKernelGGL(k_slice, dim3(B_), dim3(256), 0, stream,
                       z, yl, ru, o_zs, o_ids);
}